// Round 8
// baseline (186.111 us; speedup 1.0000x reference)
//
#include <hip/hip_runtime.h>

// Problem dims (fixed by setup_inputs)
constexpr int Bb = 4, Cc = 128, Nn = 4096, Kk = 32, Ns = 16384;
constexpr int ROWS = Bb * Nn; // 16384 (b*n) rows
constexpr float EPS = 1e-5f;

// ---- workspace layout (bytes) ----
constexpr size_t SZ_SEG   = (size_t)Bb * Ns * Cc * 4;   // 32 MB scatter-max targets
constexpr size_t OFF_SEG  = 0;
constexpr size_t SZ_GX    = (size_t)ROWS * Cc * 4;      // 8 MB
constexpr size_t OFF_GX   = OFF_SEG + SZ_SEG;
constexpr size_t SZ_PART  = (size_t)256 * 128 * 2 * 4;  // 256 KB per stats-partial set
constexpr size_t OFF_P1   = OFF_GX + SZ_GX;
constexpr size_t OFF_P2   = OFF_P1 + SZ_PART;
constexpr size_t OFF_FLAG = OFF_P2 + SZ_PART;           // 256 KB int32 verified flags
constexpr size_t OFF_CTR  = OFF_FLAG + (size_t)Bb * Ns * 4;

// ---- prep: zero the gathered seg rows, write verified flags, zero barrier ctrs ----
// Verified flag: flags[bb*Ns+fi] = i (the claiming gather-row). A stale/garbage
// entry j passes validation only if fps[j]==fi with j in batch bb -- which means
// fi IS in the set. So no clearing pass is ever needed (exact, race-free).
__global__ __launch_bounds__(256) void k_prep(const int* __restrict__ fps,
                                              float4* __restrict__ seg4,
                                              int* __restrict__ flags,
                                              unsigned int* __restrict__ ctr) {
    int i = blockIdx.x * 8 + (threadIdx.x >> 5);    // gather-row index 0..16383
    int lane = threadIdx.x & 31;
    int bb = i >> 12;
    int fi = fps[i];
    if (lane == 0) flags[bb * Ns + fi] = i;
    seg4[((size_t)bb * Ns + fi) * 32 + lane] = float4{0.f, 0.f, 0.f, 0.f};
    if (blockIdx.x == 0 && threadIdx.x < 2) ctr[threadIdx.x] = 0u;
}

// ---- fused: local max over k + filtered scatter-max into seg ----
// grid (4096, 4), 256 threads. Block = one (b, n): 128 channels x 32 k.
__global__ __launch_bounds__(256) void k_groupmax_scatter(
        const float* __restrict__ x, const int* __restrict__ gidx,
        const int* __restrict__ flags, const int* __restrict__ fps,
        float* __restrict__ gx, unsigned int* __restrict__ seg) {
    int nn = blockIdx.x, bb = blockIdx.y;
    int t = threadIdx.x;
    __shared__ float gbuf[128];
    __shared__ unsigned int srow[32];   // seg row base per k, 0xFFFFFFFF = not needed
    __shared__ float cur[32][129];      // snapshot of seg rows (padded)

    if (t < 32) {
        int idxv = gidx[((bb * Nn + nn) << 5) + t];
        int fl = flags[bb * Ns + idxv];
        int j = fl & 16383;
        bool need = ((j >> 12) == bb) && (fps[j] == idxv);
        srow[t] = need ? (unsigned int)(bb * Ns + idxv) * 128u : 0xFFFFFFFFu;
    }
    __syncthreads();

    int k4 = (t & 7) * 4;
    int cq = t >> 3;                    // 0..31
    const float* xb = x + ((size_t)bb * Cc) * (Nn * Kk) + (size_t)nn * Kk;
    float4 v[4];
    #pragma unroll
    for (int p = 0; p < 4; p++)
        v[p] = *(const float4*)(xb + (size_t)(cq + p * 32) * (Nn * Kk) + k4);

    const float* segf_ = (const float*)seg;
    #pragma unroll
    for (int i = 0; i < 4; i++) {       // snapshot: 32 rows x 128 ch, coalesced
        int flat = t + i * 256;
        int row = flat >> 5;
        int c4 = (flat & 31) * 4;
        unsigned int sr = srow[row];
        float4 c{3.0e38f, 3.0e38f, 3.0e38f, 3.0e38f};
        if (sr != 0xFFFFFFFFu) c = *(const float4*)(segf_ + sr + c4);
        cur[row][c4 + 0] = c.x; cur[row][c4 + 1] = c.y;
        cur[row][c4 + 2] = c.z; cur[row][c4 + 3] = c.w;
    }
    __syncthreads();

    unsigned int s0 = srow[k4 + 0], s1 = srow[k4 + 1];
    unsigned int s2 = srow[k4 + 2], s3 = srow[k4 + 3];

    #pragma unroll
    for (int p = 0; p < 4; p++) {
        int ch = cq + p * 32;
        float4 w = v[p];
        float m = fmaxf(fmaxf(w.x, w.y), fmaxf(w.z, w.w));
        m = fmaxf(m, __shfl_xor(m, 1, 64));
        m = fmaxf(m, __shfl_xor(m, 2, 64));
        m = fmaxf(m, __shfl_xor(m, 4, 64));
        if ((t & 7) == 0) gbuf[ch] = m;
        if (w.x > cur[k4 + 0][ch]) atomicMax(seg + s0 + ch, __float_as_uint(w.x));
        if (w.y > cur[k4 + 1][ch]) atomicMax(seg + s1 + ch, __float_as_uint(w.y));
        if (w.z > cur[k4 + 2][ch]) atomicMax(seg + s2 + ch, __float_as_uint(w.z));
        if (w.w > cur[k4 + 3][ch]) atomicMax(seg + s3 + ch, __float_as_uint(w.w));
    }
    __syncthreads();
    if (t < 128) gx[((size_t)(bb * Nn + nn)) * 128 + t] = gbuf[t];
}

// ---- mega kernel: gemm1 -> BN1 (grid barrier) -> gemm2 -> BN2 (grid barrier) -> out ----
// Block-diagonal fusion: gemm2's A-tile = this block's gemm1 output (kept in LDS,
// transposed [k][row]); h2 stays in registers. 256 blocks x 512 thr, ~61 KB LDS
// -> >=2 blocks/CU co-resident (2x margin for the spin barriers).
__global__ __launch_bounds__(512) void k_mega(
        const float* __restrict__ gx, const float* __restrict__ segf,
        const int* __restrict__ fps,
        const float* __restrict__ w1, const float* __restrict__ b1,
        const float* __restrict__ g1, const float* __restrict__ be1,
        const float* __restrict__ w2, const float* __restrict__ b2,
        const float* __restrict__ g2, const float* __restrict__ be2,
        float* __restrict__ part1, float* __restrict__ part2,
        unsigned int* __restrict__ ctr, float* __restrict__ out) {
    __shared__ float As[32][68];    // gemm1 A stage [kc][row]; reused as stats staging
    __shared__ float Bs[32][132];   // B stage [kc][col]; reused as stats staging
    __shared__ float h1t[128][68];  // h1 transposed [k][row]; reused as out tile
    __shared__ float ssc[128], ssh[128], tmp[256];
    __shared__ int rowbase[64];
    int t = threadIdx.x;
    int m0 = blockIdx.x * 64;
    if (t < 64) rowbase[t] = (((m0 + t) >> 12) * Ns + fps[m0 + t]) * 128;
    int tn = t & 31, tm = t >> 5;   // cols tn*4..+3, rows tm*4..+3
    float acc[4][4] = {};

    // ---- GEMM1: A(64x256) @ w1^T -> 64x128 ----
    for (int k0 = 0; k0 < 256; k0 += 32) {
        __syncthreads();
        {   int row = t >> 3, c4 = (t & 7) * 4, k = k0 + c4;
            float4 v;
            if (k0 < 128) v = *(const float4*)(gx + (size_t)(m0 + row) * 128 + k);
            else          v = *(const float4*)(segf + rowbase[row] + (k - 128));
            As[c4 + 0][row] = v.x; As[c4 + 1][row] = v.y;
            As[c4 + 2][row] = v.z; As[c4 + 3][row] = v.w;
        }
        #pragma unroll
        for (int i = 0; i < 2; i++) {
            int fq = t + i * 512;
            int col = fq >> 3, c4 = (fq & 7) * 4;
            float4 v = *(const float4*)(w1 + (size_t)col * 256 + k0 + c4);
            Bs[c4 + 0][col] = v.x; Bs[c4 + 1][col] = v.y;
            Bs[c4 + 2][col] = v.z; Bs[c4 + 3][col] = v.w;
        }
        __syncthreads();
        #pragma unroll
        for (int kc = 0; kc < 32; kc++) {
            float4 a = *(const float4*)&As[kc][tm * 4];
            float4 bv = *(const float4*)&Bs[kc][tn * 4];
            float av[4] = {a.x, a.y, a.z, a.w};
            float bw[4] = {bv.x, bv.y, bv.z, bv.w};
            #pragma unroll
            for (int r = 0; r < 4; r++)
                #pragma unroll
                for (int c = 0; c < 4; c++) acc[r][c] += av[r] * bw[c];
        }
    }
    // epilogue 1: bias, stats partials, store h1 (pre-BN) transposed to LDS
    {
        float4 bv = *(const float4*)(b1 + tn * 4);
        float o_[4][4];
        float s_[4] = {}, q_[4] = {};
        #pragma unroll
        for (int r = 0; r < 4; r++) {
            o_[r][0] = acc[r][0] + bv.x; o_[r][1] = acc[r][1] + bv.y;
            o_[r][2] = acc[r][2] + bv.z; o_[r][3] = acc[r][3] + bv.w;
            #pragma unroll
            for (int c = 0; c < 4; c++) { s_[c] += o_[r][c]; q_[c] += o_[r][c] * o_[r][c]; }
        }
        __syncthreads();    // As/Bs dead -> stats staging; h1t fresh
        float* reds = &As[0][0];
        float* redq = &Bs[0][0];
        #pragma unroll
        for (int c = 0; c < 4; c++) {
            reds[tm * 128 + tn * 4 + c] = s_[c];
            redq[tm * 128 + tn * 4 + c] = q_[c];
        }
        #pragma unroll
        for (int r = 0; r < 4; r++)
            #pragma unroll
            for (int c = 0; c < 4; c++)
                h1t[tn * 4 + c][tm * 4 + r] = o_[r][c];
        __syncthreads();
        if (t < 128) {
            float s = 0.f, q = 0.f;
            #pragma unroll
            for (int j = 0; j < 16; j++) { s += reds[j * 128 + t]; q += redq[j * 128 + t]; }
            part1[blockIdx.x * 128 + t] = s;
            part1[32768 + blockIdx.x * 128 + t] = q;
        }
        #pragma unroll
        for (int r = 0; r < 4; r++)
            #pragma unroll
            for (int c = 0; c < 4; c++) acc[r][c] = 0.f;
    }
    // ---- grid barrier 1 (release/acquire, agent scope: crosses XCD L2s) ----
    __syncthreads();
    if (t == 0) {
        __hip_atomic_fetch_add(&ctr[0], 1u, __ATOMIC_ACQ_REL, __HIP_MEMORY_SCOPE_AGENT);
        while (__hip_atomic_load(&ctr[0], __ATOMIC_ACQUIRE, __HIP_MEMORY_SCOPE_AGENT) < 256u)
            __builtin_amdgcn_s_sleep(2);
    }
    __syncthreads();
    // ---- BN1 finalize + apply to h1t in place ----
    if (t < 256) {
        int ch = t & 127;
        const float* src = part1 + (t >> 7) * 32768 + ch;
        float a = 0.f;
        #pragma unroll 8
        for (int j = 0; j < 256; j++) a += src[j * 128];
        tmp[t] = a;
    }
    __syncthreads();
    if (t < 128) {
        float mean = tmp[t] * (1.0f / 16384.0f);
        float var = tmp[t + 128] * (1.0f / 16384.0f) - mean * mean;
        float sc = g1[t] * rsqrtf(var + EPS);
        ssc[t] = sc;
        ssh[t] = be1[t] - mean * sc;
    }
    __syncthreads();
    {   int k = t >> 2, r0 = (t & 3) * 16;
        float sck = ssc[k], shk = ssh[k];
        #pragma unroll
        for (int e = 0; e < 16; e += 4) {
            float4 v = *(float4*)&h1t[k][r0 + e];
            v.x = fmaxf(0.f, fmaf(v.x, sck, shk));
            v.y = fmaxf(0.f, fmaf(v.y, sck, shk));
            v.z = fmaxf(0.f, fmaf(v.z, sck, shk));
            v.w = fmaxf(0.f, fmaf(v.w, sck, shk));
            *(float4*)&h1t[k][r0 + e] = v;
        }
    }
    // ---- GEMM2: relu(bn1(h1)) @ w2^T -> 64x128 (A from h1t, broadcast reads) ----
    for (int k0 = 0; k0 < 128; k0 += 32) {
        __syncthreads();
        #pragma unroll
        for (int i = 0; i < 2; i++) {
            int fq = t + i * 512;
            int col = fq >> 3, c4 = (fq & 7) * 4;
            float4 v = *(const float4*)(w2 + (size_t)col * 128 + k0 + c4);
            Bs[c4 + 0][col] = v.x; Bs[c4 + 1][col] = v.y;
            Bs[c4 + 2][col] = v.z; Bs[c4 + 3][col] = v.w;
        }
        __syncthreads();
        #pragma unroll
        for (int kc = 0; kc < 32; kc++) {
            float4 a = *(const float4*)&h1t[k0 + kc][tm * 4];
            float4 bv = *(const float4*)&Bs[kc][tn * 4];
            float av[4] = {a.x, a.y, a.z, a.w};
            float bw[4] = {bv.x, bv.y, bv.z, bv.w};
            #pragma unroll
            for (int r = 0; r < 4; r++)
                #pragma unroll
                for (int c = 0; c < 4; c++) acc[r][c] += av[r] * bw[c];
        }
    }
    // epilogue 2: bias, stats partials (h2 stays in registers)
    float o2_[4][4];
    {
        float4 bv = *(const float4*)(b2 + tn * 4);
        float s_[4] = {}, q_[4] = {};
        #pragma unroll
        for (int r = 0; r < 4; r++) {
            o2_[r][0] = acc[r][0] + bv.x; o2_[r][1] = acc[r][1] + bv.y;
            o2_[r][2] = acc[r][2] + bv.z; o2_[r][3] = acc[r][3] + bv.w;
            #pragma unroll
            for (int c = 0; c < 4; c++) { s_[c] += o2_[r][c]; q_[c] += o2_[r][c] * o2_[r][c]; }
        }
        __syncthreads();
        float* reds = &As[0][0];
        float* redq = &Bs[0][0];
        #pragma unroll
        for (int c = 0; c < 4; c++) {
            reds[tm * 128 + tn * 4 + c] = s_[c];
            redq[tm * 128 + tn * 4 + c] = q_[c];
        }
        __syncthreads();
        if (t < 128) {
            float s = 0.f, q = 0.f;
            #pragma unroll
            for (int j = 0; j < 16; j++) { s += reds[j * 128 + t]; q += redq[j * 128 + t]; }
            part2[blockIdx.x * 128 + t] = s;
            part2[32768 + blockIdx.x * 128 + t] = q;
        }
    }
    // ---- grid barrier 2 ----
    __syncthreads();
    if (t == 0) {
        __hip_atomic_fetch_add(&ctr[1], 1u, __ATOMIC_ACQ_REL, __HIP_MEMORY_SCOPE_AGENT);
        while (__hip_atomic_load(&ctr[1], __ATOMIC_ACQUIRE, __HIP_MEMORY_SCOPE_AGENT) < 256u)
            __builtin_amdgcn_s_sleep(2);
    }
    __syncthreads();
    // ---- BN2 finalize + apply + transposed coalesced write ----
    if (t < 256) {
        int ch = t & 127;
        const float* src = part2 + (t >> 7) * 32768 + ch;
        float a = 0.f;
        #pragma unroll 8
        for (int j = 0; j < 256; j++) a += src[j * 128];
        tmp[t] = a;
    }
    __syncthreads();
    if (t < 128) {
        float mean = tmp[t] * (1.0f / 16384.0f);
        float var = tmp[t + 128] * (1.0f / 16384.0f) - mean * mean;
        float sc = g2[t] * rsqrtf(var + EPS);
        ssc[t] = sc;
        ssh[t] = be2[t] - mean * sc;
    }
    __syncthreads();                // h1t dead -> out tile [64][133]
    float* flat = &h1t[0][0];
    #pragma unroll
    for (int r = 0; r < 4; r++)
        #pragma unroll
        for (int c = 0; c < 4; c++) {
            int col = tn * 4 + c;
            flat[(tm * 4 + r) * 133 + col] =
                fmaxf(0.f, fmaf(o2_[r][c], ssc[col], ssh[col]));
        }
    __syncthreads();
    {
        int j = t & 63, og = t >> 6;    // lanes sweep n for coalesced writes
        int bb = m0 >> 12, n0 = m0 & 4095;
        #pragma unroll
        for (int o = og; o < 128; o += 8)
            out[((size_t)(bb * 128 + o)) * Nn + n0 + j] = flat[j * 133 + o];
    }
}

extern "C" void kernel_launch(void* const* d_in, const int* in_sizes, int n_in,
                              void* d_out, int out_size, void* d_ws, size_t ws_size,
                              hipStream_t stream) {
    const float* x    = (const float*)d_in[0];
    const int*   gidx = (const int*)d_in[1];
    const int*   fps  = (const int*)d_in[2];
    // d_in[3] = N (16384), known statically
    const float* w1   = (const float*)d_in[4];
    const float* b1   = (const float*)d_in[5];
    const float* g1   = (const float*)d_in[6];
    const float* be1  = (const float*)d_in[7];
    const float* w2   = (const float*)d_in[8];
    const float* b2   = (const float*)d_in[9];
    const float* g2   = (const float*)d_in[10];
    const float* be2  = (const float*)d_in[11];
    float* out = (float*)d_out;

    char* ws = (char*)d_ws;
    unsigned int* seg  = (unsigned int*)(ws + OFF_SEG);
    float* segf        = (float*)(ws + OFF_SEG);
    float4* seg4       = (float4*)(ws + OFF_SEG);
    float* gx          = (float*)(ws + OFF_GX);
    float* part1       = (float*)(ws + OFF_P1);
    float* part2       = (float*)(ws + OFF_P2);
    int* flags         = (int*)(ws + OFF_FLAG);
    unsigned int* ctr  = (unsigned int*)(ws + OFF_CTR);

    k_prep<<<ROWS / 8, 256, 0, stream>>>(fps, seg4, flags, ctr);
    k_groupmax_scatter<<<dim3(Nn, Bb), 256, 0, stream>>>(x, gidx, flags, fps, gx, seg);
    k_mega<<<ROWS / 64, 512, 0, stream>>>(gx, segf, fps, w1, b1, g1, be1,
                                          w2, b2, g2, be2, part1, part2, ctr, out);
}

// Round 9
// 168.564 us; speedup vs baseline: 1.1041x; 1.1041x over previous
//
#include <hip/hip_runtime.h>

// Problem dims (fixed by setup_inputs)
constexpr int Bb = 4, Cc = 128, Nn = 4096, Kk = 32, Ns = 16384;
constexpr int ROWS = Bb * Nn; // 16384 (b*n) rows
constexpr float EPS = 1e-5f;

// ---- workspace layout (bytes) ----
constexpr size_t SZ_SEG   = (size_t)Bb * Ns * Cc * 4;   // 32 MB scatter-max targets
constexpr size_t OFF_SEG  = 0;
constexpr size_t SZ_GX    = (size_t)ROWS * Cc * 4;      // 8 MB
constexpr size_t OFF_GX   = OFF_SEG + SZ_SEG;
constexpr size_t OFF_H1   = OFF_GX + SZ_GX;
constexpr size_t OFF_H2   = OFF_H1 + SZ_GX;
constexpr size_t SZ_PART  = (size_t)256 * 128 * 2 * 4;  // 256 KB per stats-partial set
constexpr size_t OFF_P1   = OFF_H2 + SZ_GX;
constexpr size_t OFF_P2   = OFF_P1 + SZ_PART;
constexpr size_t OFF_FLAG = OFF_P2 + SZ_PART;           // 256 KB int32 verified flags

// ---- prep: zero gathered seg rows + write verified flags (no clearing needed) ----
// flags[bb*Ns+fi] = i (claiming gather-row). Garbage entry j validates only if
// fps[j]==fi with j in batch bb -- which itself proves fi is in the set, and
// in-set entries are always overwritten by prep. Exact, race-free, clear-free.
__global__ __launch_bounds__(256) void k_prep(const int* __restrict__ fps,
                                              float4* __restrict__ seg4,
                                              int* __restrict__ flags) {
    int i = blockIdx.x * 8 + (threadIdx.x >> 5);    // gather-row index 0..16383
    int lane = threadIdx.x & 31;
    int bb = i >> 12;
    int fi = fps[i];
    if (lane == 0) flags[bb * Ns + fi] = i;
    seg4[((size_t)bb * Ns + fi) * 32 + lane] = float4{0.f, 0.f, 0.f, 0.f};
}

// ---- fused: local max over k + flag-filtered scatter-max, 4 n-points/block ----
// grid (1024, 4), 256 threads. Thread t: channel cq=t>>3 (+32/pass), k-quad (t&7)*4.
// 16 independent float4 x-loads issued up front (4 points x 4 channel-passes);
// points are contiguous in x -> each wave reads full 512B segments per channel.
__global__ __launch_bounds__(256) void k_groupmax_scatter(
        const float* __restrict__ x, const int* __restrict__ gidx,
        const int* __restrict__ flags, const int* __restrict__ fps,
        float* __restrict__ gx, unsigned int* __restrict__ seg) {
    int nn0 = blockIdx.x * 4, bb = blockIdx.y;
    int t = threadIdx.x;
    __shared__ float gbuf[4][128];
    __shared__ unsigned int srow[4][32];    // seg row base per (point, k); ~0u = skip

    int k4 = (t & 7) * 4;
    int cq = t >> 3;                        // 0..31
    const float* xb = x + (size_t)bb * Cc * (Nn * Kk) + (size_t)nn0 * Kk;
    float4 v[4][4];
    #pragma unroll
    for (int pt = 0; pt < 4; pt++)
        #pragma unroll
        for (int p = 0; p < 4; p++)
            v[pt][p] = *(const float4*)(xb + (size_t)(cq + p * 32) * (Nn * Kk) + pt * Kk + k4);

    if (t < 128) {
        int pt = t >> 5, kk = t & 31;
        int idxv = gidx[((bb * Nn + nn0 + pt) << 5) + kk];
        int fl = flags[bb * Ns + idxv];
        int j = fl & 16383;
        bool need = ((j >> 12) == bb) && (fps[j] == idxv);
        srow[pt][kk] = need ? (unsigned int)(bb * Ns + idxv) * 128u : 0xFFFFFFFFu;
    }
    __syncthreads();

    #pragma unroll
    for (int pt = 0; pt < 4; pt++) {
        unsigned int s0 = srow[pt][k4 + 0], s1 = srow[pt][k4 + 1];
        unsigned int s2 = srow[pt][k4 + 2], s3 = srow[pt][k4 + 3];
        #pragma unroll
        for (int p = 0; p < 4; p++) {
            int ch = cq + p * 32;
            float4 w = v[pt][p];
            float m = fmaxf(fmaxf(w.x, w.y), fmaxf(w.z, w.w));
            m = fmaxf(m, __shfl_xor(m, 1, 64));
            m = fmaxf(m, __shfl_xor(m, 2, 64));
            m = fmaxf(m, __shfl_xor(m, 4, 64));
            if ((t & 7) == 0) gbuf[pt][ch] = m;
            if (s0 != 0xFFFFFFFFu && w.x > 0.f) atomicMax(seg + s0 + ch, __float_as_uint(w.x));
            if (s1 != 0xFFFFFFFFu && w.y > 0.f) atomicMax(seg + s1 + ch, __float_as_uint(w.y));
            if (s2 != 0xFFFFFFFFu && w.z > 0.f) atomicMax(seg + s2 + ch, __float_as_uint(w.z));
            if (s3 != 0xFFFFFFFFu && w.w > 0.f) atomicMax(seg + s3 + ch, __float_as_uint(w.w));
        }
    }
    __syncthreads();
    #pragma unroll
    for (int i = 0; i < 2; i++) {
        int idx = t + i * 256;
        int pt = idx >> 7, ch = idx & 127;
        gx[((size_t)(bb * Nn + nn0 + pt)) * 128 + ch] = gbuf[pt][ch];
    }
}

// ---- GEMM1: h1(row,128) = A(row,256) @ w1^T + b1 ; per-block BN partials ----
// 512 threads (8 waves), 64x128 tile, grid 256.
__global__ __launch_bounds__(512) void k_gemm1(
        const float* __restrict__ gx, const float* __restrict__ segf,
        const int* __restrict__ fps, const float* __restrict__ w1,
        const float* __restrict__ b1, float* __restrict__ h1,
        float* __restrict__ part) {
    __shared__ float As[32][68];    // [kc][row]
    __shared__ float Bs[32][132];   // [kc][col]
    __shared__ int rowbase[64];
    int t = threadIdx.x;
    int m0 = blockIdx.x * 64;
    if (t < 64) {
        int row = m0 + t;
        rowbase[t] = ((row >> 12) * Ns + fps[row]) * 128;
    }
    int tn = t & 31;    // cols tn*4..+3
    int tm = t >> 5;    // 0..15, rows tm*4..+3
    float acc[4][4] = {};
    for (int k0 = 0; k0 < 256; k0 += 32) {
        __syncthreads();
        {                                       // A: 2048 floats, 1 float4/thread
            int row = t >> 3;
            int c4 = (t & 7) * 4;
            int k = k0 + c4;
            float4 v;
            if (k0 < 128) v = *(const float4*)(gx + (size_t)(m0 + row) * 128 + k);
            else          v = *(const float4*)(segf + rowbase[row] + (k - 128));
            As[c4 + 0][row] = v.x; As[c4 + 1][row] = v.y;
            As[c4 + 2][row] = v.z; As[c4 + 3][row] = v.w;
        }
        #pragma unroll
        for (int i = 0; i < 2; i++) {           // B: 4096 floats
            int fq = t + i * 512;
            int col = fq >> 3;
            int c4 = (fq & 7) * 4;
            float4 v = *(const float4*)(w1 + (size_t)col * 256 + k0 + c4);
            Bs[c4 + 0][col] = v.x; Bs[c4 + 1][col] = v.y;
            Bs[c4 + 2][col] = v.z; Bs[c4 + 3][col] = v.w;
        }
        __syncthreads();
        #pragma unroll
        for (int kc = 0; kc < 32; kc++) {
            float4 a = *(const float4*)&As[kc][tm * 4];
            float4 bv = *(const float4*)&Bs[kc][tn * 4];
            float av[4] = {a.x, a.y, a.z, a.w};
            float bw[4] = {bv.x, bv.y, bv.z, bv.w};
            #pragma unroll
            for (int r = 0; r < 4; r++)
                #pragma unroll
                for (int c = 0; c < 4; c++) acc[r][c] += av[r] * bw[c];
        }
    }
    float4 bv = *(const float4*)(b1 + tn * 4);
    float s_[4] = {}, q_[4] = {};
    #pragma unroll
    for (int r = 0; r < 4; r++) {
        int row = m0 + tm * 4 + r;
        float o0 = acc[r][0] + bv.x, o1 = acc[r][1] + bv.y;
        float o2 = acc[r][2] + bv.z, o3 = acc[r][3] + bv.w;
        float4 o{o0, o1, o2, o3};
        *(float4*)(h1 + (size_t)row * 128 + tn * 4) = o;
        s_[0] += o0; s_[1] += o1; s_[2] += o2; s_[3] += o3;
        q_[0] += o0 * o0; q_[1] += o1 * o1; q_[2] += o2 * o2; q_[3] += o3 * o3;
    }
    __syncthreads();
    float* reds = &As[0][0];    // 2176 >= 16*128
    float* redq = &Bs[0][0];    // 4224 >= 16*128
    #pragma unroll
    for (int c = 0; c < 4; c++) {
        reds[tm * 128 + tn * 4 + c] = s_[c];
        redq[tm * 128 + tn * 4 + c] = q_[c];
    }
    __syncthreads();
    if (t < 128) {
        float s = 0.f, q = 0.f;
        #pragma unroll
        for (int j = 0; j < 16; j++) { s += reds[j * 128 + t]; q += redq[j * 128 + t]; }
        part[blockIdx.x * 128 + t] = s;
        part[32768 + blockIdx.x * 128 + t] = q;
    }
}

// ---- GEMM2: inline BN1 finalize, h2 = relu(bn1(h1)) @ w2^T + b2 ; BN2 partials ----
__global__ __launch_bounds__(512) void k_gemm2(
        const float* __restrict__ h1, const float* __restrict__ part1,
        const float* __restrict__ g1, const float* __restrict__ be1,
        const float* __restrict__ w2, const float* __restrict__ b2,
        float* __restrict__ h2, float* __restrict__ part2) {
    __shared__ float As[32][68];
    __shared__ float Bs[32][132];
    __shared__ float ssc[128], ssh[128], tmp[256];
    int t = threadIdx.x;
    int m0 = blockIdx.x * 64;
    if (t < 256) {          // inline finalize of BN1 stats
        int ch = t & 127;
        const float* src = part1 + (t >> 7) * 32768 + ch;
        float a = 0.f;
        #pragma unroll 8
        for (int j = 0; j < 256; j++) a += src[j * 128];
        tmp[t] = a;
    }
    __syncthreads();
    if (t < 128) {
        float mean = tmp[t] * (1.0f / 16384.0f);
        float var = tmp[t + 128] * (1.0f / 16384.0f) - mean * mean;
        float sc = g1[t] * rsqrtf(var + EPS);
        ssc[t] = sc;
        ssh[t] = be1[t] - mean * sc;
    }
    int tn = t & 31, tm = t >> 5;
    float acc[4][4] = {};
    for (int k0 = 0; k0 < 128; k0 += 32) {
        __syncthreads();
        {
            int row = t >> 3;
            int c4 = (t & 7) * 4;
            int k = k0 + c4;
            float4 v = *(const float4*)(h1 + (size_t)(m0 + row) * 128 + k);
            As[c4 + 0][row] = fmaxf(0.f, fmaf(v.x, ssc[k + 0], ssh[k + 0]));
            As[c4 + 1][row] = fmaxf(0.f, fmaf(v.y, ssc[k + 1], ssh[k + 1]));
            As[c4 + 2][row] = fmaxf(0.f, fmaf(v.z, ssc[k + 2], ssh[k + 2]));
            As[c4 + 3][row] = fmaxf(0.f, fmaf(v.w, ssc[k + 3], ssh[k + 3]));
        }
        #pragma unroll
        for (int i = 0; i < 2; i++) {
            int fq = t + i * 512;
            int col = fq >> 3;
            int c4 = (fq & 7) * 4;
            float4 v = *(const float4*)(w2 + (size_t)col * 128 + k0 + c4);
            Bs[c4 + 0][col] = v.x; Bs[c4 + 1][col] = v.y;
            Bs[c4 + 2][col] = v.z; Bs[c4 + 3][col] = v.w;
        }
        __syncthreads();
        #pragma unroll
        for (int kc = 0; kc < 32; kc++) {
            float4 a = *(const float4*)&As[kc][tm * 4];
            float4 bv = *(const float4*)&Bs[kc][tn * 4];
            float av[4] = {a.x, a.y, a.z, a.w};
            float bw[4] = {bv.x, bv.y, bv.z, bv.w};
            #pragma unroll
            for (int r = 0; r < 4; r++)
                #pragma unroll
                for (int c = 0; c < 4; c++) acc[r][c] += av[r] * bw[c];
        }
    }
    float4 bv = *(const float4*)(b2 + tn * 4);
    float s_[4] = {}, q_[4] = {};
    #pragma unroll
    for (int r = 0; r < 4; r++) {
        int row = m0 + tm * 4 + r;
        float o0 = acc[r][0] + bv.x, o1 = acc[r][1] + bv.y;
        float o2 = acc[r][2] + bv.z, o3 = acc[r][3] + bv.w;
        float4 o{o0, o1, o2, o3};
        *(float4*)(h2 + (size_t)row * 128 + tn * 4) = o;
        s_[0] += o0; s_[1] += o1; s_[2] += o2; s_[3] += o3;
        q_[0] += o0 * o0; q_[1] += o1 * o1; q_[2] += o2 * o2; q_[3] += o3 * o3;
    }
    __syncthreads();
    float* reds = &As[0][0];
    float* redq = &Bs[0][0];
    #pragma unroll
    for (int c = 0; c < 4; c++) {
        reds[tm * 128 + tn * 4 + c] = s_[c];
        redq[tm * 128 + tn * 4 + c] = q_[c];
    }
    __syncthreads();
    if (t < 128) {
        float s = 0.f, q = 0.f;
        #pragma unroll
        for (int j = 0; j < 16; j++) { s += reds[j * 128 + t]; q += redq[j * 128 + t]; }
        part2[blockIdx.x * 128 + t] = s;
        part2[32768 + blockIdx.x * 128 + t] = q;
    }
}

// ---- final: inline BN2 finalize, bn2+relu on h2, transpose to (b, c, n) ----
__global__ __launch_bounds__(512) void k_out(const float* __restrict__ h2,
                                             const float* __restrict__ part2,
                                             const float* __restrict__ g2,
                                             const float* __restrict__ be2,
                                             float* __restrict__ out) {
    __shared__ float tile[64][129];
    __shared__ float lsc[128], lsh[128], tmp[256];
    int t = threadIdx.x;
    int bb = blockIdx.y, n0 = blockIdx.x * 64;
    if (t < 256) {
        int ch = t & 127;
        const float* src = part2 + (t >> 7) * 32768 + ch;
        float a = 0.f;
        #pragma unroll 8
        for (int j = 0; j < 256; j++) a += src[j * 128];
        tmp[t] = a;
    }
    __syncthreads();
    if (t < 128) {
        float mean = tmp[t] * (1.0f / 16384.0f);
        float var = tmp[t + 128] * (1.0f / 16384.0f) - mean * mean;
        float sc = g2[t] * rsqrtf(var + EPS);
        lsc[t] = sc;
        lsh[t] = be2[t] - mean * sc;
    }
    #pragma unroll
    for (int i = 0; i < 4; i++) {               // load 64 rows x 128 ch
        int fq = t + i * 512;
        int row = fq >> 5;
        int c4 = (fq & 31) * 4;
        float4 v = *(const float4*)(h2 + ((size_t)(bb * Nn + n0 + row)) * 128 + c4);
        tile[row][c4 + 0] = v.x; tile[row][c4 + 1] = v.y;
        tile[row][c4 + 2] = v.z; tile[row][c4 + 3] = v.w;
    }
    __syncthreads();
    int j = t & 63, og = t >> 6;                // lanes sweep n for coalesced writes
    #pragma unroll
    for (int o = og; o < 128; o += 8) {
        float v = fmaxf(0.f, fmaf(tile[j][o], lsc[o], lsh[o]));
        out[((size_t)(bb * 128 + o)) * Nn + n0 + j] = v;
    }
}

extern "C" void kernel_launch(void* const* d_in, const int* in_sizes, int n_in,
                              void* d_out, int out_size, void* d_ws, size_t ws_size,
                              hipStream_t stream) {
    const float* x    = (const float*)d_in[0];
    const int*   gidx = (const int*)d_in[1];
    const int*   fps  = (const int*)d_in[2];
    // d_in[3] = N (16384), known statically
    const float* w1   = (const float*)d_in[4];
    const float* b1   = (const float*)d_in[5];
    const float* g1   = (const float*)d_in[6];
    const float* be1  = (const float*)d_in[7];
    const float* w2   = (const float*)d_in[8];
    const float* b2   = (const float*)d_in[9];
    const float* g2   = (const float*)d_in[10];
    const float* be2  = (const float*)d_in[11];
    float* out = (float*)d_out;

    char* ws = (char*)d_ws;
    unsigned int* seg  = (unsigned int*)(ws + OFF_SEG);
    float* segf        = (float*)(ws + OFF_SEG);
    float4* seg4       = (float4*)(ws + OFF_SEG);
    float* gx          = (float*)(ws + OFF_GX);
    float* h1          = (float*)(ws + OFF_H1);
    float* h2          = (float*)(ws + OFF_H2);
    float* part1       = (float*)(ws + OFF_P1);
    float* part2       = (float*)(ws + OFF_P2);
    int* flags         = (int*)(ws + OFF_FLAG);

    k_prep<<<ROWS / 8, 256, 0, stream>>>(fps, seg4, flags);
    k_groupmax_scatter<<<dim3(Nn / 4, Bb), 256, 0, stream>>>(x, gidx, flags, fps, gx, seg);
    k_gemm1<<<ROWS / 64, 512, 0, stream>>>(gx, segf, fps, w1, b1, h1, part1);
    k_gemm2<<<ROWS / 64, 512, 0, stream>>>(h1, part1, g1, be1, w2, b2, h2, part2);
    k_out<<<dim3(Nn / 64, Bb), 512, 0, stream>>>(h2, part2, g2, be2, out);
}